// Round 13
// baseline (88.638 us; speedup 1.0000x reference)
//
#include <hip/hip_runtime.h>

// Pipeline (see reference):
//   bins = clip(|x|,0,20)  -> one-hot conv == per-pixel gather of w0[o, bin(tap), k]
//   stage0 kernel: build folded fp16 table tab[k][bin][o] + packed-fp16 w1 pairs in d_ws
//   stage1 kernel: fused layer0 (dil-8 3x3, BN0 folded) + layer1 (1x1 64->4, s1 folded
//                  outside o-loop) + block rearrange (x qtable) + 1x1 512->3 (+b2, BN2)
//                  -> z [8,3,64,64] f32 in d_ws
//   stage2 kernel: bilinear x8 upsample (half-pixel centers, edge clamp) -> d_out
//
// R13 = R12 with ONE change: launch_bounds (512,6) -> (512,8).
//   R12 counters: VALUBusy 60%, est LDS ~50%, Occupancy 50% -> latency-bound,
//   neither pipe saturated. Measured VGPR=40 fits the 64-VGPR budget of 8
//   waves/SIMD (R5's spill was a heavier variant); LDS 26.6KB x 4 blocks = 106KB
//   < 160KB; 4 blocks x 8 waves = 32 waves/CU (100% cap). More waves -> better
//   VALU/DS overlap. Everything else verbatim from the passing R12.
//   - OSTRIDE 66 halves = 33 dwords (ODD): row bank = kb mod 32; a tap's 22 rows
//     are consecutive kb -> distinct banks; same-bin lanes broadcast. Conflicts ~0.
//   - per tap per quad: two adjacent 4B LDS reads -> fused ds_read2_b32.
//   - w1 stage via v_dot2_f32_f16 (f32 accumulate), w1 pairs scalar-loaded.

#define NB_BINS 22   // 21 real bins + sentinel bin 21 for out-of-bounds taps
#define OSTRIDE 66   // 64 channels + 2 pad halves: 33 dwords/row, odd -> distinct banks
#define TAB_N   (9 * NB_BINS * OSTRIDE)   // halves

typedef _Float16 h2 __attribute__((ext_vector_type(2)));
typedef float f4 __attribute__((ext_vector_type(4)));

__device__ inline h2 pkmax0(h2 a) {
    unsigned r, ua = __builtin_bit_cast(unsigned, a);
    asm("v_pk_max_f16 %0, %1, %2" : "=v"(r) : "v"(ua), "v"(0u));
    return __builtin_bit_cast(h2, r);
}
#define H2(u) __builtin_bit_cast(h2, (u))

__global__ __launch_bounds__(256) void build_tab(
    const float* __restrict__ w0,   // [64,21,3,3]
    const float* __restrict__ b0,
    const float* __restrict__ s0,
    const float* __restrict__ t0,
    const float* __restrict__ w1,   // [4,64]
    _Float16* __restrict__ tabg)    // [9*22*66] + 128 packed w1 pairs
{
    const int tid = threadIdx.x;
    for (int t = tid; t < 9 * NB_BINS * 64; t += 256) {
        int kb = t >> 6;              // k*22 + bin
        int o  = t & 63;
        int k   = kb / NB_BINS;
        int bin = kb - k * NB_BINS;
        float g0 = fmaf(s0[o], b0[o], t0[o]) * (1.0f / 9.0f);
        float val = g0;
        if (bin < 21) {
            int ky = k / 3, kx = k - ky * 3;
            val = fmaf(s0[o], w0[((o * 21 + bin) * 3 + ky) * 3 + kx], g0);
        }
        tabg[kb * OSTRIDE + o] = (_Float16)val;
    }
    // packed w1 pairs: w1h[c*32 + p] = (f16(w1[c][2p]), f16(w1[c][2p+1]))
    if (tid < 128) {
        int c = tid >> 5, p = tid & 31;
        h2 v;
        v.x = (_Float16)w1[c * 64 + 2 * p];
        v.y = (_Float16)w1[c * 64 + 2 * p + 1];
        ((unsigned*)(tabg + TAB_N))[tid] = __builtin_bit_cast(unsigned, v);
    }
}

template <bool PRE>
__global__ __launch_bounds__(512, 8) void dct_stage1(
    const int* __restrict__ xin,      // [8,1,512,512] int32
    const float* __restrict__ qtable, // [8,8,8]
    const float* __restrict__ w0,     // [64,21,3,3]
    const float* __restrict__ b0,     // [64]
    const float* __restrict__ s0,     // [64]
    const float* __restrict__ t0,     // [64]
    const float* __restrict__ w1,     // [4,64]
    const float* __restrict__ s1,     // [4]
    const float* __restrict__ t1,     // [4]
    const float* __restrict__ w2,     // [3,512]
    const float* __restrict__ b2,     // [3]
    const float* __restrict__ s2,     // [3]
    const float* __restrict__ t2,     // [3]
    const _Float16* __restrict__ tabg,
    float* __restrict__ zout)         // [8,3,64,64]
{
    // tab[k][bin][o] = fp16( s0[o]*w0[o][bin][ky][kx] + g0[o]/9 )  (bin < 21)
    //               = fp16( g0[o]/9 )                              (bin == 21, OOB)
    // g0 = s0*b0 + t0.  Sum over 9 taps == s0*conv + g0 (up to fp16 rounding).
    __shared__ _Float16 tab[TAB_N];   // 26,136 B shared by 8 waves

    const int tid = threadIdx.x;
    const int bid = blockIdx.x;       // 2048 workgroups: (b, hb, seg)
    const int b   = bid >> 8;
    const int hb  = (bid >> 2) & 63;
    const int seg = bid & 3;

    if (PRE) {
        const unsigned* tg = (const unsigned*)tabg;
        unsigned* tl = (unsigned*)tab;
        for (int t = tid; t < TAB_N / 2; t += 512) tl[t] = tg[t];
    } else {
        for (int t = tid; t < 9 * NB_BINS * 64; t += 512) {
            int kb = t >> 6;
            int o  = t & 63;
            int k   = kb / NB_BINS;
            int bin = kb - k * NB_BINS;
            float g0 = fmaf(s0[o], b0[o], t0[o]) * (1.0f / 9.0f);
            float val = g0;
            if (bin < 21) {
                int ky = k / 3, kx = k - ky * 3;
                val = fmaf(s0[o], w0[((o * 21 + bin) * 3 + ky) * 3 + kx], g0);
            }
            tab[kb * OSTRIDE + o] = (_Float16)val;
        }
    }
    __syncthreads();

    const int lane = tid & 63;
    const int wave = tid >> 6;        // 0..7
    const int i = lane >> 3;          // row within 8x8 block
    const int j = lane & 7;           // col within 8x8 block

    // Per-lane constants for the block-rearrange + 512->3 conv.
    // z channel index = c*64 + i*8 + j (= c*64 + lane); channels 256.. get *qtable.
    const float q = qtable[b * 64 + lane];
    float A[3][4], Bq[3][4];
#pragma unroll
    for (int oc = 0; oc < 3; ++oc) {
        float s = s2[oc];
#pragma unroll
        for (int c = 0; c < 4; ++c) {
            A[oc][c]  = s * w2[oc * 512 + c * 64 + lane];
            Bq[oc][c] = s * w2[oc * 512 + 256 + c * 64 + lane];
        }
    }
    const float zc0 = fmaf(s2[0], b2[0], t2[0]);
    const float zc1 = fmaf(s2[1], b2[1], t2[1]);
    const float zc2 = fmaf(s2[2], b2[2], t2[2]);
    const float s1r0 = s1[0], s1r1 = s1[1], s1r2 = s1[2], s1r3 = s1[3];
    const float t1r0 = t1[0], t1r1 = t1[1], t1r2 = t1[2], t1r3 = t1[3];

    const int y = hb * 8 + i;
    const int* xin_b = xin + b * 512 * 512;
    const unsigned* w1h = (const unsigned*)(tabg + TAB_N);  // packed pairs (PRE only)

    for (int t = 0; t < 2; ++t) {
        const int wb = seg * 16 + wave * 2 + t;   // 4 segs x 8 waves x 2 -> 64 blocks
        const int xc = wb * 8 + j;

        // 9 tap bins -> 9 named LDS row base pointers (SSA scalars, no array!)
        const _Float16 *tp0, *tp1, *tp2, *tp3, *tp4, *tp5, *tp6, *tp7, *tp8;
#define TAP(K, DY, DX)                                                      \
        {                                                                   \
            int yy = y + (DY), xx = xc + (DX);                              \
            int bin = 21;                                                   \
            if ((unsigned)yy < 512u && (unsigned)xx < 512u) {               \
                int v = xin_b[yy * 512 + xx];                               \
                v = v < 0 ? -v : v;                                         \
                bin = v > 20 ? 20 : v;                                      \
            }                                                               \
            tp##K = &tab[((K) * NB_BINS + bin) * OSTRIDE];                  \
        }
        TAP(0, -8, -8) TAP(1, -8, 0) TAP(2, -8, 8)
        TAP(3,  0, -8) TAP(4,  0, 0) TAP(5,  0, 8)
        TAP(6,  8, -8) TAP(7,  8, 0) TAP(8,  8, 8)
#undef TAP

        float d0 = 0.f, d1 = 0.f, d2 = 0.f, d3 = 0.f;
#pragma unroll 2
        for (int c4 = 0; c4 < 16; ++c4) {
            const int e = c4 * 4;     // first channel of this quad
            // per tap: two adjacent 4B LDS reads -> fused ds_read2_b32
            unsigned l0 = *(const unsigned*)(tp0 + e), h0 = *(const unsigned*)(tp0 + e + 2);
            unsigned l1 = *(const unsigned*)(tp1 + e), h1 = *(const unsigned*)(tp1 + e + 2);
            unsigned l2 = *(const unsigned*)(tp2 + e), h2_ = *(const unsigned*)(tp2 + e + 2);
            unsigned l3 = *(const unsigned*)(tp3 + e), h3 = *(const unsigned*)(tp3 + e + 2);
            unsigned l4 = *(const unsigned*)(tp4 + e), h4 = *(const unsigned*)(tp4 + e + 2);
            unsigned l5 = *(const unsigned*)(tp5 + e), h5 = *(const unsigned*)(tp5 + e + 2);
            unsigned l6 = *(const unsigned*)(tp6 + e), h6 = *(const unsigned*)(tp6 + e + 2);
            unsigned l7 = *(const unsigned*)(tp7 + e), h7 = *(const unsigned*)(tp7 + e + 2);
            unsigned l8 = *(const unsigned*)(tp8 + e), h8 = *(const unsigned*)(tp8 + e + 2);
            h2 aL = ((H2(l0) + H2(l1)) + (H2(l2) + H2(l3)))
                  + ((H2(l4) + H2(l5)) + (H2(l6) + H2(l7))) + H2(l8);
            h2 aH = ((H2(h0) + H2(h1)) + (H2(h2_) + H2(h3)))
                  + ((H2(h4) + H2(h5)) + (H2(h6) + H2(h7))) + H2(h8);
            aL = pkmax0(aL);          // relu(s0*conv0 + s0*b0 + t0), packed
            aH = pkmax0(aH);
            if (PRE) {
                // w1 dot via v_dot2_f32_f16: f32 acc, packed f16 operands,
                // w1 pairs scalar-loaded (uniform addr) -> 8 VALU per quad
                const int pe = c4 * 2;
                d0 = __builtin_amdgcn_fdot2(aL, H2(w1h[0 * 32 + pe]), d0, false);
                d0 = __builtin_amdgcn_fdot2(aH, H2(w1h[0 * 32 + pe + 1]), d0, false);
                d1 = __builtin_amdgcn_fdot2(aL, H2(w1h[1 * 32 + pe]), d1, false);
                d1 = __builtin_amdgcn_fdot2(aH, H2(w1h[1 * 32 + pe + 1]), d1, false);
                d2 = __builtin_amdgcn_fdot2(aL, H2(w1h[2 * 32 + pe]), d2, false);
                d2 = __builtin_amdgcn_fdot2(aH, H2(w1h[2 * 32 + pe + 1]), d2, false);
                d3 = __builtin_amdgcn_fdot2(aL, H2(w1h[3 * 32 + pe]), d3, false);
                d3 = __builtin_amdgcn_fdot2(aH, H2(w1h[3 * 32 + pe + 1]), d3, false);
            } else {
                float v0 = (float)aL.x, v1 = (float)aL.y;
                float v2 = (float)aH.x, v3 = (float)aH.y;
                d0 = fmaf(w1[0*64+e+3], v3, fmaf(w1[0*64+e+2], v2,
                     fmaf(w1[0*64+e+1], v1, fmaf(w1[0*64+e+0], v0, d0))));
                d1 = fmaf(w1[1*64+e+3], v3, fmaf(w1[1*64+e+2], v2,
                     fmaf(w1[1*64+e+1], v1, fmaf(w1[1*64+e+0], v0, d1))));
                d2 = fmaf(w1[2*64+e+3], v3, fmaf(w1[2*64+e+2], v2,
                     fmaf(w1[2*64+e+1], v1, fmaf(w1[2*64+e+0], v0, d2))));
                d3 = fmaf(w1[3*64+e+3], v3, fmaf(w1[3*64+e+2], v2,
                     fmaf(w1[3*64+e+1], v1, fmaf(w1[3*64+e+0], v0, d3))));
            }
        }
        // relu(s1*conv1 + t1) with s1 folded outside the loop
        float u0 = fmaxf(fmaf(s1r0, d0, t1r0), 0.0f);
        float u1 = fmaxf(fmaf(s1r1, d1, t1r1), 0.0f);
        float u2 = fmaxf(fmaf(s1r2, d2, t1r2), 0.0f);
        float u3 = fmaxf(fmaf(s1r3, d3, t1r3), 0.0f);
        const float uq0 = u0 * q, uq1 = u1 * q, uq2 = u2 * q, uq3 = u3 * q;

        float p0, p1, p2;
        p0 = A[0][0] * u0 + A[0][1] * u1 + A[0][2] * u2 + A[0][3] * u3
           + Bq[0][0] * uq0 + Bq[0][1] * uq1 + Bq[0][2] * uq2 + Bq[0][3] * uq3;
        p1 = A[1][0] * u0 + A[1][1] * u1 + A[1][2] * u2 + A[1][3] * u3
           + Bq[1][0] * uq0 + Bq[1][1] * uq1 + Bq[1][2] * uq2 + Bq[1][3] * uq3;
        p2 = A[2][0] * u0 + A[2][1] * u1 + A[2][2] * u2 + A[2][3] * u3
           + Bq[2][0] * uq0 + Bq[2][1] * uq1 + Bq[2][2] * uq2 + Bq[2][3] * uq3;
#pragma unroll
        for (int m = 1; m < 64; m <<= 1) {
            p0 += __shfl_xor(p0, m);
            p1 += __shfl_xor(p1, m);
            p2 += __shfl_xor(p2, m);
        }
        if (lane == 0) {
            zout[((b * 3 + 0) * 64 + hb) * 64 + wb] = p0 + zc0;
            zout[((b * 3 + 1) * 64 + hb) * 64 + wb] = p1 + zc1;
            zout[((b * 3 + 2) * 64 + hb) * 64 + wb] = p2 + zc2;
        }
    }
}

// Bilinear x8 upsample, half-pixel centers (align_corners=False), edge clamp.
// src = (dst + 0.5)/8 - 0.5; weights periodic with dst%8.
// 8 outputs per thread (one x8-aligned run): needs only 3 source columns x 2 rows.
__global__ __launch_bounds__(256) void upsample8(
    const float* __restrict__ z,   // [8,3,64,64]
    float* __restrict__ out)       // [8,3,512,512]
{
    const int idx = blockIdx.x * 256 + threadIdx.x;   // 786,432 threads, 8 outs each
    const int xb    = idx & 63;           // source tile column
    const int rest  = idx >> 6;
    const int yy    = rest & 511;
    const int plane = rest >> 9;          // b*3 + oc, 0..23

    const float* zp = z + plane * 4096;

    const int yb = yy >> 3, r = yy & 7;
    int y0; float fy;
    if (r < 4) { y0 = yb - 1; fy = (2 * r + 9) * (1.0f / 16.0f); }
    else       { y0 = yb;     fy = (2 * r - 7) * (1.0f / 16.0f); }
    int y1 = y0 + 1;
    y0 = y0 < 0 ? 0 : y0;
    y1 = y1 > 63 ? 63 : y1;
    const float* row0 = zp + y0 * 64;
    const float* row1 = zp + y1 * 64;

    const int xm = xb > 0 ? xb - 1 : 0;
    const int xp = xb < 63 ? xb + 1 : 63;
    const float l0 = row0[xm], c0 = row0[xb], r0 = row0[xp];
    const float l1 = row1[xm], c1 = row1[xb], r1 = row1[xp];

    f4 resA, resB;
#pragma unroll
    for (int rr = 0; rr < 4; ++rr) {
        float fx = (2 * rr + 9) * (1.0f / 16.0f);
        float v0 = l0 + fx * (c0 - l0);
        float v1 = l1 + fx * (c1 - l1);
        resA[rr] = v0 + fy * (v1 - v0);
    }
#pragma unroll
    for (int rr = 0; rr < 4; ++rr) {
        float fx = (2 * rr + 1) * (1.0f / 16.0f);
        float v0 = c0 + fx * (r0 - c0);
        float v1 = c1 + fx * (r1 - c1);
        resB[rr] = v0 + fy * (v1 - v0);
    }
    f4* dst = (f4*)&out[idx * 8];
    __builtin_nontemporal_store(resA, dst);
    __builtin_nontemporal_store(resB, dst + 1);
}

extern "C" void kernel_launch(void* const* d_in, const int* in_sizes, int n_in,
                              void* d_out, int out_size, void* d_ws, size_t ws_size,
                              hipStream_t stream) {
    const int*   x      = (const int*)d_in[0];
    const float* qtable = (const float*)d_in[1];
    const float* w0     = (const float*)d_in[2];
    const float* b0     = (const float*)d_in[3];
    const float* s0     = (const float*)d_in[4];
    const float* t0     = (const float*)d_in[5];
    const float* w1     = (const float*)d_in[6];
    const float* s1     = (const float*)d_in[7];
    const float* t1     = (const float*)d_in[8];
    const float* w2     = (const float*)d_in[9];
    const float* b2     = (const float*)d_in[10];
    const float* s2     = (const float*)d_in[11];
    const float* t2     = (const float*)d_in[12];

    float*    zbuf = (float*)d_ws;                       // 393,216 B
    _Float16* tabg = (_Float16*)((char*)d_ws + 393216);  // + 26,136 B + 512 B w1h
    float*    out  = (float*)d_out;

    const bool pre = ws_size >= (size_t)(393216 + TAB_N * 2 + 512);
    if (pre) {
        build_tab<<<1, 256, 0, stream>>>(w0, b0, s0, t0, w1, tabg);
        dct_stage1<true><<<2048, 512, 0, stream>>>(x, qtable, w0, b0, s0, t0,
                                                   w1, s1, t1, w2, b2, s2, t2,
                                                   tabg, zbuf);
    } else {
        dct_stage1<false><<<2048, 512, 0, stream>>>(x, qtable, w0, b0, s0, t0,
                                                    w1, s1, t1, w2, b2, s2, t2,
                                                    nullptr, zbuf);
    }
    upsample8<<<3072, 256, 0, stream>>>(zbuf, out);
}

// Round 14
// 78.803 us; speedup vs baseline: 1.1248x; 1.1248x over previous
//
#include <hip/hip_runtime.h>

// Pipeline (see reference):
//   bins = clip(|x|,0,20)  -> one-hot conv == per-pixel gather of w0[o, bin(tap), k]
//   stage0 kernel: build folded fp16 table tab[k][bin][o] + packed-fp16 w1 pairs in d_ws
//   stage1 kernel: fused layer0 (dil-8 3x3, BN0 folded) + layer1 (1x1 64->4, s1 folded
//                  outside o-loop) + block rearrange (x qtable) + 1x1 512->3 (+b2, BN2)
//                  -> z [8,3,64,64] f32 in d_ws
//   stage2 kernel: bilinear x8 upsample (half-pixel centers, edge clamp) -> d_out
//
// R14 = R12 with ONE change: launch_bounds (512,6) -> (512,4).
//   Empirical launch_bounds semantics (R5/R12/R13 evidence): 2nd arg acts as min
//   BLOCKS/CU. (512,8) -> 64 waves/CU infeasible -> compiler budgeted 32 VGPR ->
//   spill (R13: WRITE 94MB). (512,4) -> 4 blocks x 8 waves = 32 waves/CU (HW cap),
//   VGPR budget 64 >= the 40 this kernel needs -> no spill, full occupancy.
//   LDS 26.6KB x 4 = 106KB < 160KB. Everything else verbatim from passing R12.
//   - OSTRIDE 66 halves = 33 dwords (ODD): row bank = kb mod 32; a tap's 22 rows
//     are consecutive kb -> distinct banks; same-bin lanes broadcast. Conflicts ~0.
//   - per tap per quad: two adjacent 4B LDS reads -> fused ds_read2_b32.
//   - w1 stage via v_dot2_f32_f16 (f32 accumulate), w1 pairs scalar-loaded.

#define NB_BINS 22   // 21 real bins + sentinel bin 21 for out-of-bounds taps
#define OSTRIDE 66   // 64 channels + 2 pad halves: 33 dwords/row, odd -> distinct banks
#define TAB_N   (9 * NB_BINS * OSTRIDE)   // halves

typedef _Float16 h2 __attribute__((ext_vector_type(2)));
typedef float f4 __attribute__((ext_vector_type(4)));

__device__ inline h2 pkmax0(h2 a) {
    unsigned r, ua = __builtin_bit_cast(unsigned, a);
    asm("v_pk_max_f16 %0, %1, %2" : "=v"(r) : "v"(ua), "v"(0u));
    return __builtin_bit_cast(h2, r);
}
#define H2(u) __builtin_bit_cast(h2, (u))

__global__ __launch_bounds__(256) void build_tab(
    const float* __restrict__ w0,   // [64,21,3,3]
    const float* __restrict__ b0,
    const float* __restrict__ s0,
    const float* __restrict__ t0,
    const float* __restrict__ w1,   // [4,64]
    _Float16* __restrict__ tabg)    // [9*22*66] + 128 packed w1 pairs
{
    const int tid = threadIdx.x;
    for (int t = tid; t < 9 * NB_BINS * 64; t += 256) {
        int kb = t >> 6;              // k*22 + bin
        int o  = t & 63;
        int k   = kb / NB_BINS;
        int bin = kb - k * NB_BINS;
        float g0 = fmaf(s0[o], b0[o], t0[o]) * (1.0f / 9.0f);
        float val = g0;
        if (bin < 21) {
            int ky = k / 3, kx = k - ky * 3;
            val = fmaf(s0[o], w0[((o * 21 + bin) * 3 + ky) * 3 + kx], g0);
        }
        tabg[kb * OSTRIDE + o] = (_Float16)val;
    }
    // packed w1 pairs: w1h[c*32 + p] = (f16(w1[c][2p]), f16(w1[c][2p+1]))
    if (tid < 128) {
        int c = tid >> 5, p = tid & 31;
        h2 v;
        v.x = (_Float16)w1[c * 64 + 2 * p];
        v.y = (_Float16)w1[c * 64 + 2 * p + 1];
        ((unsigned*)(tabg + TAB_N))[tid] = __builtin_bit_cast(unsigned, v);
    }
}

template <bool PRE>
__global__ __launch_bounds__(512, 4) void dct_stage1(
    const int* __restrict__ xin,      // [8,1,512,512] int32
    const float* __restrict__ qtable, // [8,8,8]
    const float* __restrict__ w0,     // [64,21,3,3]
    const float* __restrict__ b0,     // [64]
    const float* __restrict__ s0,     // [64]
    const float* __restrict__ t0,     // [64]
    const float* __restrict__ w1,     // [4,64]
    const float* __restrict__ s1,     // [4]
    const float* __restrict__ t1,     // [4]
    const float* __restrict__ w2,     // [3,512]
    const float* __restrict__ b2,     // [3]
    const float* __restrict__ s2,     // [3]
    const float* __restrict__ t2,     // [3]
    const _Float16* __restrict__ tabg,
    float* __restrict__ zout)         // [8,3,64,64]
{
    // tab[k][bin][o] = fp16( s0[o]*w0[o][bin][ky][kx] + g0[o]/9 )  (bin < 21)
    //               = fp16( g0[o]/9 )                              (bin == 21, OOB)
    // g0 = s0*b0 + t0.  Sum over 9 taps == s0*conv + g0 (up to fp16 rounding).
    __shared__ _Float16 tab[TAB_N];   // 26,136 B shared by 8 waves

    const int tid = threadIdx.x;
    const int bid = blockIdx.x;       // 2048 workgroups: (b, hb, seg)
    const int b   = bid >> 8;
    const int hb  = (bid >> 2) & 63;
    const int seg = bid & 3;

    if (PRE) {
        const unsigned* tg = (const unsigned*)tabg;
        unsigned* tl = (unsigned*)tab;
        for (int t = tid; t < TAB_N / 2; t += 512) tl[t] = tg[t];
    } else {
        for (int t = tid; t < 9 * NB_BINS * 64; t += 512) {
            int kb = t >> 6;
            int o  = t & 63;
            int k   = kb / NB_BINS;
            int bin = kb - k * NB_BINS;
            float g0 = fmaf(s0[o], b0[o], t0[o]) * (1.0f / 9.0f);
            float val = g0;
            if (bin < 21) {
                int ky = k / 3, kx = k - ky * 3;
                val = fmaf(s0[o], w0[((o * 21 + bin) * 3 + ky) * 3 + kx], g0);
            }
            tab[kb * OSTRIDE + o] = (_Float16)val;
        }
    }
    __syncthreads();

    const int lane = tid & 63;
    const int wave = tid >> 6;        // 0..7
    const int i = lane >> 3;          // row within 8x8 block
    const int j = lane & 7;           // col within 8x8 block

    // Per-lane constants for the block-rearrange + 512->3 conv.
    // z channel index = c*64 + i*8 + j (= c*64 + lane); channels 256.. get *qtable.
    const float q = qtable[b * 64 + lane];
    float A[3][4], Bq[3][4];
#pragma unroll
    for (int oc = 0; oc < 3; ++oc) {
        float s = s2[oc];
#pragma unroll
        for (int c = 0; c < 4; ++c) {
            A[oc][c]  = s * w2[oc * 512 + c * 64 + lane];
            Bq[oc][c] = s * w2[oc * 512 + 256 + c * 64 + lane];
        }
    }
    const float zc0 = fmaf(s2[0], b2[0], t2[0]);
    const float zc1 = fmaf(s2[1], b2[1], t2[1]);
    const float zc2 = fmaf(s2[2], b2[2], t2[2]);
    const float s1r0 = s1[0], s1r1 = s1[1], s1r2 = s1[2], s1r3 = s1[3];
    const float t1r0 = t1[0], t1r1 = t1[1], t1r2 = t1[2], t1r3 = t1[3];

    const int y = hb * 8 + i;
    const int* xin_b = xin + b * 512 * 512;
    const unsigned* w1h = (const unsigned*)(tabg + TAB_N);  // packed pairs (PRE only)

    for (int t = 0; t < 2; ++t) {
        const int wb = seg * 16 + wave * 2 + t;   // 4 segs x 8 waves x 2 -> 64 blocks
        const int xc = wb * 8 + j;

        // 9 tap bins -> 9 named LDS row base pointers (SSA scalars, no array!)
        const _Float16 *tp0, *tp1, *tp2, *tp3, *tp4, *tp5, *tp6, *tp7, *tp8;
#define TAP(K, DY, DX)                                                      \
        {                                                                   \
            int yy = y + (DY), xx = xc + (DX);                              \
            int bin = 21;                                                   \
            if ((unsigned)yy < 512u && (unsigned)xx < 512u) {               \
                int v = xin_b[yy * 512 + xx];                               \
                v = v < 0 ? -v : v;                                         \
                bin = v > 20 ? 20 : v;                                      \
            }                                                               \
            tp##K = &tab[((K) * NB_BINS + bin) * OSTRIDE];                  \
        }
        TAP(0, -8, -8) TAP(1, -8, 0) TAP(2, -8, 8)
        TAP(3,  0, -8) TAP(4,  0, 0) TAP(5,  0, 8)
        TAP(6,  8, -8) TAP(7,  8, 0) TAP(8,  8, 8)
#undef TAP

        float d0 = 0.f, d1 = 0.f, d2 = 0.f, d3 = 0.f;
#pragma unroll 2
        for (int c4 = 0; c4 < 16; ++c4) {
            const int e = c4 * 4;     // first channel of this quad
            // per tap: two adjacent 4B LDS reads -> fused ds_read2_b32
            unsigned l0 = *(const unsigned*)(tp0 + e), h0 = *(const unsigned*)(tp0 + e + 2);
            unsigned l1 = *(const unsigned*)(tp1 + e), h1 = *(const unsigned*)(tp1 + e + 2);
            unsigned l2 = *(const unsigned*)(tp2 + e), h2_ = *(const unsigned*)(tp2 + e + 2);
            unsigned l3 = *(const unsigned*)(tp3 + e), h3 = *(const unsigned*)(tp3 + e + 2);
            unsigned l4 = *(const unsigned*)(tp4 + e), h4 = *(const unsigned*)(tp4 + e + 2);
            unsigned l5 = *(const unsigned*)(tp5 + e), h5 = *(const unsigned*)(tp5 + e + 2);
            unsigned l6 = *(const unsigned*)(tp6 + e), h6 = *(const unsigned*)(tp6 + e + 2);
            unsigned l7 = *(const unsigned*)(tp7 + e), h7 = *(const unsigned*)(tp7 + e + 2);
            unsigned l8 = *(const unsigned*)(tp8 + e), h8 = *(const unsigned*)(tp8 + e + 2);
            h2 aL = ((H2(l0) + H2(l1)) + (H2(l2) + H2(l3)))
                  + ((H2(l4) + H2(l5)) + (H2(l6) + H2(l7))) + H2(l8);
            h2 aH = ((H2(h0) + H2(h1)) + (H2(h2_) + H2(h3)))
                  + ((H2(h4) + H2(h5)) + (H2(h6) + H2(h7))) + H2(h8);
            aL = pkmax0(aL);          // relu(s0*conv0 + s0*b0 + t0), packed
            aH = pkmax0(aH);
            if (PRE) {
                // w1 dot via v_dot2_f32_f16: f32 acc, packed f16 operands,
                // w1 pairs scalar-loaded (uniform addr) -> 8 VALU per quad
                const int pe = c4 * 2;
                d0 = __builtin_amdgcn_fdot2(aL, H2(w1h[0 * 32 + pe]), d0, false);
                d0 = __builtin_amdgcn_fdot2(aH, H2(w1h[0 * 32 + pe + 1]), d0, false);
                d1 = __builtin_amdgcn_fdot2(aL, H2(w1h[1 * 32 + pe]), d1, false);
                d1 = __builtin_amdgcn_fdot2(aH, H2(w1h[1 * 32 + pe + 1]), d1, false);
                d2 = __builtin_amdgcn_fdot2(aL, H2(w1h[2 * 32 + pe]), d2, false);
                d2 = __builtin_amdgcn_fdot2(aH, H2(w1h[2 * 32 + pe + 1]), d2, false);
                d3 = __builtin_amdgcn_fdot2(aL, H2(w1h[3 * 32 + pe]), d3, false);
                d3 = __builtin_amdgcn_fdot2(aH, H2(w1h[3 * 32 + pe + 1]), d3, false);
            } else {
                float v0 = (float)aL.x, v1 = (float)aL.y;
                float v2 = (float)aH.x, v3 = (float)aH.y;
                d0 = fmaf(w1[0*64+e+3], v3, fmaf(w1[0*64+e+2], v2,
                     fmaf(w1[0*64+e+1], v1, fmaf(w1[0*64+e+0], v0, d0))));
                d1 = fmaf(w1[1*64+e+3], v3, fmaf(w1[1*64+e+2], v2,
                     fmaf(w1[1*64+e+1], v1, fmaf(w1[1*64+e+0], v0, d1))));
                d2 = fmaf(w1[2*64+e+3], v3, fmaf(w1[2*64+e+2], v2,
                     fmaf(w1[2*64+e+1], v1, fmaf(w1[2*64+e+0], v0, d2))));
                d3 = fmaf(w1[3*64+e+3], v3, fmaf(w1[3*64+e+2], v2,
                     fmaf(w1[3*64+e+1], v1, fmaf(w1[3*64+e+0], v0, d3))));
            }
        }
        // relu(s1*conv1 + t1) with s1 folded outside the loop
        float u0 = fmaxf(fmaf(s1r0, d0, t1r0), 0.0f);
        float u1 = fmaxf(fmaf(s1r1, d1, t1r1), 0.0f);
        float u2 = fmaxf(fmaf(s1r2, d2, t1r2), 0.0f);
        float u3 = fmaxf(fmaf(s1r3, d3, t1r3), 0.0f);
        const float uq0 = u0 * q, uq1 = u1 * q, uq2 = u2 * q, uq3 = u3 * q;

        float p0, p1, p2;
        p0 = A[0][0] * u0 + A[0][1] * u1 + A[0][2] * u2 + A[0][3] * u3
           + Bq[0][0] * uq0 + Bq[0][1] * uq1 + Bq[0][2] * uq2 + Bq[0][3] * uq3;
        p1 = A[1][0] * u0 + A[1][1] * u1 + A[1][2] * u2 + A[1][3] * u3
           + Bq[1][0] * uq0 + Bq[1][1] * uq1 + Bq[1][2] * uq2 + Bq[1][3] * uq3;
        p2 = A[2][0] * u0 + A[2][1] * u1 + A[2][2] * u2 + A[2][3] * u3
           + Bq[2][0] * uq0 + Bq[2][1] * uq1 + Bq[2][2] * uq2 + Bq[2][3] * uq3;
#pragma unroll
        for (int m = 1; m < 64; m <<= 1) {
            p0 += __shfl_xor(p0, m);
            p1 += __shfl_xor(p1, m);
            p2 += __shfl_xor(p2, m);
        }
        if (lane == 0) {
            zout[((b * 3 + 0) * 64 + hb) * 64 + wb] = p0 + zc0;
            zout[((b * 3 + 1) * 64 + hb) * 64 + wb] = p1 + zc1;
            zout[((b * 3 + 2) * 64 + hb) * 64 + wb] = p2 + zc2;
        }
    }
}

// Bilinear x8 upsample, half-pixel centers (align_corners=False), edge clamp.
// src = (dst + 0.5)/8 - 0.5; weights periodic with dst%8.
// 8 outputs per thread (one x8-aligned run): needs only 3 source columns x 2 rows.
__global__ __launch_bounds__(256) void upsample8(
    const float* __restrict__ z,   // [8,3,64,64]
    float* __restrict__ out)       // [8,3,512,512]
{
    const int idx = blockIdx.x * 256 + threadIdx.x;   // 786,432 threads, 8 outs each
    const int xb    = idx & 63;           // source tile column
    const int rest  = idx >> 6;
    const int yy    = rest & 511;
    const int plane = rest >> 9;          // b*3 + oc, 0..23

    const float* zp = z + plane * 4096;

    const int yb = yy >> 3, r = yy & 7;
    int y0; float fy;
    if (r < 4) { y0 = yb - 1; fy = (2 * r + 9) * (1.0f / 16.0f); }
    else       { y0 = yb;     fy = (2 * r - 7) * (1.0f / 16.0f); }
    int y1 = y0 + 1;
    y0 = y0 < 0 ? 0 : y0;
    y1 = y1 > 63 ? 63 : y1;
    const float* row0 = zp + y0 * 64;
    const float* row1 = zp + y1 * 64;

    const int xm = xb > 0 ? xb - 1 : 0;
    const int xp = xb < 63 ? xb + 1 : 63;
    const float l0 = row0[xm], c0 = row0[xb], r0 = row0[xp];
    const float l1 = row1[xm], c1 = row1[xb], r1 = row1[xp];

    f4 resA, resB;
#pragma unroll
    for (int rr = 0; rr < 4; ++rr) {
        float fx = (2 * rr + 9) * (1.0f / 16.0f);
        float v0 = l0 + fx * (c0 - l0);
        float v1 = l1 + fx * (c1 - l1);
        resA[rr] = v0 + fy * (v1 - v0);
    }
#pragma unroll
    for (int rr = 0; rr < 4; ++rr) {
        float fx = (2 * rr + 1) * (1.0f / 16.0f);
        float v0 = c0 + fx * (r0 - c0);
        float v1 = c1 + fx * (r1 - c1);
        resB[rr] = v0 + fy * (v1 - v0);
    }
    f4* dst = (f4*)&out[idx * 8];
    __builtin_nontemporal_store(resA, dst);
    __builtin_nontemporal_store(resB, dst + 1);
}

extern "C" void kernel_launch(void* const* d_in, const int* in_sizes, int n_in,
                              void* d_out, int out_size, void* d_ws, size_t ws_size,
                              hipStream_t stream) {
    const int*   x      = (const int*)d_in[0];
    const float* qtable = (const float*)d_in[1];
    const float* w0     = (const float*)d_in[2];
    const float* b0     = (const float*)d_in[3];
    const float* s0     = (const float*)d_in[4];
    const float* t0     = (const float*)d_in[5];
    const float* w1     = (const float*)d_in[6];
    const float* s1     = (const float*)d_in[7];
    const float* t1     = (const float*)d_in[8];
    const float* w2     = (const float*)d_in[9];
    const float* b2     = (const float*)d_in[10];
    const float* s2     = (const float*)d_in[11];
    const float* t2     = (const float*)d_in[12];

    float*    zbuf = (float*)d_ws;                       // 393,216 B
    _Float16* tabg = (_Float16*)((char*)d_ws + 393216);  // + 26,136 B + 512 B w1h
    float*    out  = (float*)d_out;

    const bool pre = ws_size >= (size_t)(393216 + TAB_N * 2 + 512);
    if (pre) {
        build_tab<<<1, 256, 0, stream>>>(w0, b0, s0, t0, w1, tabg);
        dct_stage1<true><<<2048, 512, 0, stream>>>(x, qtable, w0, b0, s0, t0,
                                                   w1, s1, t1, w2, b2, s2, t2,
                                                   tabg, zbuf);
    } else {
        dct_stage1<false><<<2048, 512, 0, stream>>>(x, qtable, w0, b0, s0, t0,
                                                    w1, s1, t1, w2, b2, s2, t2,
                                                    nullptr, zbuf);
    }
    upsample8<<<3072, 256, 0, stream>>>(zbuf, out);
}

// Round 15
// 68.153 us; speedup vs baseline: 1.3006x; 1.1563x over previous
//
#include <hip/hip_runtime.h>

// Pipeline (see reference):
//   bins = clip(|x|,0,20)  -> one-hot conv == per-pixel gather of w0[o, bin(tap), k]
//   stage0 kernel: build folded fp16 table tab[k][bin][o] + packed-fp16 w1 pairs in d_ws
//   stage1 kernel: fused layer0 (dil-8 3x3, BN0 folded) + layer1 (1x1 64->4, s1 folded
//                  outside o-loop) + block rearrange (x qtable) + 1x1 512->3 (+b2, BN2)
//                  -> z [8,3,64,64] f32 in d_ws
//   stage2 kernel: bilinear x8 upsample (half-pixel centers, edge clamp) -> d_out
//
// R15: stage1 is at its LDS-instruction-issue roofline (144 ds_read2_b32/tile x
// ~8.1cyc x 128 tiles/CU = 149K cyc = measured 62us; pipe ~100% busy). Wider reads
// are structurally blocked: >=8B/lane needs even-dword stride -> 22 bins on <=16
// bank classes -> real conflicts (R4: 1.26e7, R8: 1.67e7 cyc) that wipe the gain.
// So keep R12's stage1 VERBATIM (512,6) and shave the ~12.7us tail:
//   - upsample: 16 outputs/thread (8 wide x 2 rows sharing y0), y-interp 3 cols
//     then x-interp (22 lerps/16 outs vs 32), 6 loads/16 outs, 4 coalesced
//     nontemporal f4 stores.
//   - build_tab widened 1 -> 50 blocks (was a serial single-CU prologue).

#define NB_BINS 22   // 21 real bins + sentinel bin 21 for out-of-bounds taps
#define OSTRIDE 66   // 64 channels + 2 pad halves: 33 dwords/row, odd -> distinct banks
#define TAB_N   (9 * NB_BINS * OSTRIDE)   // halves

typedef _Float16 h2 __attribute__((ext_vector_type(2)));
typedef float f4 __attribute__((ext_vector_type(4)));

__device__ inline h2 pkmax0(h2 a) {
    unsigned r, ua = __builtin_bit_cast(unsigned, a);
    asm("v_pk_max_f16 %0, %1, %2" : "=v"(r) : "v"(ua), "v"(0u));
    return __builtin_bit_cast(h2, r);
}
#define H2(u) __builtin_bit_cast(h2, (u))

__global__ __launch_bounds__(256) void build_tab(
    const float* __restrict__ w0,   // [64,21,3,3]
    const float* __restrict__ b0,
    const float* __restrict__ s0,
    const float* __restrict__ t0,
    const float* __restrict__ w1,   // [4,64]
    _Float16* __restrict__ tabg)    // [9*22*66] + 128 packed w1 pairs
{
    const int t = blockIdx.x * 256 + threadIdx.x;   // 50 blocks x 256 = 12800
    if (t < 9 * NB_BINS * 64) {
        int kb = t >> 6;              // k*22 + bin
        int o  = t & 63;
        int k   = kb / NB_BINS;
        int bin = kb - k * NB_BINS;
        float g0 = fmaf(s0[o], b0[o], t0[o]) * (1.0f / 9.0f);
        float val = g0;
        if (bin < 21) {
            int ky = k / 3, kx = k - ky * 3;
            val = fmaf(s0[o], w0[((o * 21 + bin) * 3 + ky) * 3 + kx], g0);
        }
        tabg[kb * OSTRIDE + o] = (_Float16)val;
    } else if (t - 9 * NB_BINS * 64 < 128) {
        // packed w1 pairs: w1h[c*32 + p] = (f16(w1[c][2p]), f16(w1[c][2p+1]))
        int i = t - 9 * NB_BINS * 64;
        int c = i >> 5, p = i & 31;
        h2 v;
        v.x = (_Float16)w1[c * 64 + 2 * p];
        v.y = (_Float16)w1[c * 64 + 2 * p + 1];
        ((unsigned*)(tabg + TAB_N))[i] = __builtin_bit_cast(unsigned, v);
    }
}

template <bool PRE>
__global__ __launch_bounds__(512, 6) void dct_stage1(
    const int* __restrict__ xin,      // [8,1,512,512] int32
    const float* __restrict__ qtable, // [8,8,8]
    const float* __restrict__ w0,     // [64,21,3,3]
    const float* __restrict__ b0,     // [64]
    const float* __restrict__ s0,     // [64]
    const float* __restrict__ t0,     // [64]
    const float* __restrict__ w1,     // [4,64]
    const float* __restrict__ s1,     // [4]
    const float* __restrict__ t1,     // [4]
    const float* __restrict__ w2,     // [3,512]
    const float* __restrict__ b2,     // [3]
    const float* __restrict__ s2,     // [3]
    const float* __restrict__ t2,     // [3]
    const _Float16* __restrict__ tabg,
    float* __restrict__ zout)         // [8,3,64,64]
{
    // tab[k][bin][o] = fp16( s0[o]*w0[o][bin][ky][kx] + g0[o]/9 )  (bin < 21)
    //               = fp16( g0[o]/9 )                              (bin == 21, OOB)
    // g0 = s0*b0 + t0.  Sum over 9 taps == s0*conv + g0 (up to fp16 rounding).
    __shared__ _Float16 tab[TAB_N];   // 26,136 B shared by 8 waves

    const int tid = threadIdx.x;
    const int bid = blockIdx.x;       // 2048 workgroups: (b, hb, seg)
    const int b   = bid >> 8;
    const int hb  = (bid >> 2) & 63;
    const int seg = bid & 3;

    if (PRE) {
        const unsigned* tg = (const unsigned*)tabg;
        unsigned* tl = (unsigned*)tab;
        for (int t = tid; t < TAB_N / 2; t += 512) tl[t] = tg[t];
    } else {
        for (int t = tid; t < 9 * NB_BINS * 64; t += 512) {
            int kb = t >> 6;
            int o  = t & 63;
            int k   = kb / NB_BINS;
            int bin = kb - k * NB_BINS;
            float g0 = fmaf(s0[o], b0[o], t0[o]) * (1.0f / 9.0f);
            float val = g0;
            if (bin < 21) {
                int ky = k / 3, kx = k - ky * 3;
                val = fmaf(s0[o], w0[((o * 21 + bin) * 3 + ky) * 3 + kx], g0);
            }
            tab[kb * OSTRIDE + o] = (_Float16)val;
        }
    }
    __syncthreads();

    const int lane = tid & 63;
    const int wave = tid >> 6;        // 0..7
    const int i = lane >> 3;          // row within 8x8 block
    const int j = lane & 7;           // col within 8x8 block

    // Per-lane constants for the block-rearrange + 512->3 conv.
    // z channel index = c*64 + i*8 + j (= c*64 + lane); channels 256.. get *qtable.
    const float q = qtable[b * 64 + lane];
    float A[3][4], Bq[3][4];
#pragma unroll
    for (int oc = 0; oc < 3; ++oc) {
        float s = s2[oc];
#pragma unroll
        for (int c = 0; c < 4; ++c) {
            A[oc][c]  = s * w2[oc * 512 + c * 64 + lane];
            Bq[oc][c] = s * w2[oc * 512 + 256 + c * 64 + lane];
        }
    }
    const float zc0 = fmaf(s2[0], b2[0], t2[0]);
    const float zc1 = fmaf(s2[1], b2[1], t2[1]);
    const float zc2 = fmaf(s2[2], b2[2], t2[2]);
    const float s1r0 = s1[0], s1r1 = s1[1], s1r2 = s1[2], s1r3 = s1[3];
    const float t1r0 = t1[0], t1r1 = t1[1], t1r2 = t1[2], t1r3 = t1[3];

    const int y = hb * 8 + i;
    const int* xin_b = xin + b * 512 * 512;
    const unsigned* w1h = (const unsigned*)(tabg + TAB_N);  // packed pairs (PRE only)

    for (int t = 0; t < 2; ++t) {
        const int wb = seg * 16 + wave * 2 + t;   // 4 segs x 8 waves x 2 -> 64 blocks
        const int xc = wb * 8 + j;

        // 9 tap bins -> 9 named LDS row base pointers (SSA scalars, no array!)
        const _Float16 *tp0, *tp1, *tp2, *tp3, *tp4, *tp5, *tp6, *tp7, *tp8;
#define TAP(K, DY, DX)                                                      \
        {                                                                   \
            int yy = y + (DY), xx = xc + (DX);                              \
            int bin = 21;                                                   \
            if ((unsigned)yy < 512u && (unsigned)xx < 512u) {               \
                int v = xin_b[yy * 512 + xx];                               \
                v = v < 0 ? -v : v;                                         \
                bin = v > 20 ? 20 : v;                                      \
            }                                                               \
            tp##K = &tab[((K) * NB_BINS + bin) * OSTRIDE];                  \
        }
        TAP(0, -8, -8) TAP(1, -8, 0) TAP(2, -8, 8)
        TAP(3,  0, -8) TAP(4,  0, 0) TAP(5,  0, 8)
        TAP(6,  8, -8) TAP(7,  8, 0) TAP(8,  8, 8)
#undef TAP

        float d0 = 0.f, d1 = 0.f, d2 = 0.f, d3 = 0.f;
#pragma unroll 2
        for (int c4 = 0; c4 < 16; ++c4) {
            const int e = c4 * 4;     // first channel of this quad
            // per tap: two adjacent 4B LDS reads -> fused ds_read2_b32
            unsigned l0 = *(const unsigned*)(tp0 + e), h0 = *(const unsigned*)(tp0 + e + 2);
            unsigned l1 = *(const unsigned*)(tp1 + e), h1 = *(const unsigned*)(tp1 + e + 2);
            unsigned l2 = *(const unsigned*)(tp2 + e), h2_ = *(const unsigned*)(tp2 + e + 2);
            unsigned l3 = *(const unsigned*)(tp3 + e), h3 = *(const unsigned*)(tp3 + e + 2);
            unsigned l4 = *(const unsigned*)(tp4 + e), h4 = *(const unsigned*)(tp4 + e + 2);
            unsigned l5 = *(const unsigned*)(tp5 + e), h5 = *(const unsigned*)(tp5 + e + 2);
            unsigned l6 = *(const unsigned*)(tp6 + e), h6 = *(const unsigned*)(tp6 + e + 2);
            unsigned l7 = *(const unsigned*)(tp7 + e), h7 = *(const unsigned*)(tp7 + e + 2);
            unsigned l8 = *(const unsigned*)(tp8 + e), h8 = *(const unsigned*)(tp8 + e + 2);
            h2 aL = ((H2(l0) + H2(l1)) + (H2(l2) + H2(l3)))
                  + ((H2(l4) + H2(l5)) + (H2(l6) + H2(l7))) + H2(l8);
            h2 aH = ((H2(h0) + H2(h1)) + (H2(h2_) + H2(h3)))
                  + ((H2(h4) + H2(h5)) + (H2(h6) + H2(h7))) + H2(h8);
            aL = pkmax0(aL);          // relu(s0*conv0 + s0*b0 + t0), packed
            aH = pkmax0(aH);
            if (PRE) {
                // w1 dot via v_dot2_f32_f16: f32 acc, packed f16 operands,
                // w1 pairs scalar-loaded (uniform addr) -> 8 VALU per quad
                const int pe = c4 * 2;
                d0 = __builtin_amdgcn_fdot2(aL, H2(w1h[0 * 32 + pe]), d0, false);
                d0 = __builtin_amdgcn_fdot2(aH, H2(w1h[0 * 32 + pe + 1]), d0, false);
                d1 = __builtin_amdgcn_fdot2(aL, H2(w1h[1 * 32 + pe]), d1, false);
                d1 = __builtin_amdgcn_fdot2(aH, H2(w1h[1 * 32 + pe + 1]), d1, false);
                d2 = __builtin_amdgcn_fdot2(aL, H2(w1h[2 * 32 + pe]), d2, false);
                d2 = __builtin_amdgcn_fdot2(aH, H2(w1h[2 * 32 + pe + 1]), d2, false);
                d3 = __builtin_amdgcn_fdot2(aL, H2(w1h[3 * 32 + pe]), d3, false);
                d3 = __builtin_amdgcn_fdot2(aH, H2(w1h[3 * 32 + pe + 1]), d3, false);
            } else {
                float v0 = (float)aL.x, v1 = (float)aL.y;
                float v2 = (float)aH.x, v3 = (float)aH.y;
                d0 = fmaf(w1[0*64+e+3], v3, fmaf(w1[0*64+e+2], v2,
                     fmaf(w1[0*64+e+1], v1, fmaf(w1[0*64+e+0], v0, d0))));
                d1 = fmaf(w1[1*64+e+3], v3, fmaf(w1[1*64+e+2], v2,
                     fmaf(w1[1*64+e+1], v1, fmaf(w1[1*64+e+0], v0, d1))));
                d2 = fmaf(w1[2*64+e+3], v3, fmaf(w1[2*64+e+2], v2,
                     fmaf(w1[2*64+e+1], v1, fmaf(w1[2*64+e+0], v0, d2))));
                d3 = fmaf(w1[3*64+e+3], v3, fmaf(w1[3*64+e+2], v2,
                     fmaf(w1[3*64+e+1], v1, fmaf(w1[3*64+e+0], v0, d3))));
            }
        }
        // relu(s1*conv1 + t1) with s1 folded outside the loop
        float u0 = fmaxf(fmaf(s1r0, d0, t1r0), 0.0f);
        float u1 = fmaxf(fmaf(s1r1, d1, t1r1), 0.0f);
        float u2 = fmaxf(fmaf(s1r2, d2, t1r2), 0.0f);
        float u3 = fmaxf(fmaf(s1r3, d3, t1r3), 0.0f);
        const float uq0 = u0 * q, uq1 = u1 * q, uq2 = u2 * q, uq3 = u3 * q;

        float p0, p1, p2;
        p0 = A[0][0] * u0 + A[0][1] * u1 + A[0][2] * u2 + A[0][3] * u3
           + Bq[0][0] * uq0 + Bq[0][1] * uq1 + Bq[0][2] * uq2 + Bq[0][3] * uq3;
        p1 = A[1][0] * u0 + A[1][1] * u1 + A[1][2] * u2 + A[1][3] * u3
           + Bq[1][0] * uq0 + Bq[1][1] * uq1 + Bq[1][2] * uq2 + Bq[1][3] * uq3;
        p2 = A[2][0] * u0 + A[2][1] * u1 + A[2][2] * u2 + A[2][3] * u3
           + Bq[2][0] * uq0 + Bq[2][1] * uq1 + Bq[2][2] * uq2 + Bq[2][3] * uq3;
#pragma unroll
        for (int m = 1; m < 64; m <<= 1) {
            p0 += __shfl_xor(p0, m);
            p1 += __shfl_xor(p1, m);
            p2 += __shfl_xor(p2, m);
        }
        if (lane == 0) {
            zout[((b * 3 + 0) * 64 + hb) * 64 + wb] = p0 + zc0;
            zout[((b * 3 + 1) * 64 + hb) * 64 + wb] = p1 + zc1;
            zout[((b * 3 + 2) * 64 + hb) * 64 + wb] = p2 + zc2;
        }
    }
}

// Bilinear x8 upsample, half-pixel centers (align_corners=False), edge clamp.
// src = (dst + 0.5)/8 - 0.5; weights periodic with dst%8.
// 16 outputs/thread: one x8-aligned run x 2 dst rows that share y0 (rows 2q,2q+1
// stay within the same r<4 / r>=4 half). 6 loads per 16 outputs; y-interp the 3
// columns first, then x-interp (11 lerps/row vs 16).
__global__ __launch_bounds__(256) void upsample16(
    const float* __restrict__ z,   // [8,3,64,64]
    float* __restrict__ out)       // [8,3,512,512]
{
    const int idx = blockIdx.x * 256 + threadIdx.x;   // 393,216 threads
    const int xb    = idx & 63;           // source tile column
    const int rest  = idx >> 6;
    const int q     = rest & 3;           // dst row pair: rows 2q, 2q+1
    const int rest2 = rest >> 2;
    const int yb    = rest2 & 63;         // source tile row
    const int plane = rest2 >> 6;         // b*3 + oc, 0..23

    const float* zp = z + plane * 4096;

    int y0 = (q < 2) ? yb - 1 : yb;       // rows 0..3 -> yb-1; rows 4..7 -> yb
    int y1 = y0 + 1;
    y0 = y0 < 0 ? 0 : y0;
    y1 = y1 > 63 ? 63 : y1;
    const float* row0 = zp + y0 * 64;
    const float* row1 = zp + y1 * 64;

    const int xm = xb > 0 ? xb - 1 : 0;
    const int xp = xb < 63 ? xb + 1 : 63;
    const float l0 = row0[xm], c0 = row0[xb], r0 = row0[xp];
    const float l1 = row1[xm], c1 = row1[xb], r1 = row1[xp];

    const int outbase = (plane * 512 + yb * 8 + q * 2) * 512 + xb * 8;
#pragma unroll
    for (int rl = 0; rl < 2; ++rl) {
        const int r = q * 2 + rl;
        const float fy = (r < 4) ? (2 * r + 9) * (1.0f / 16.0f)
                                 : (2 * r - 7) * (1.0f / 16.0f);
        // y-interp the three source columns once per row
        const float L = l0 + fy * (l1 - l0);
        const float C = c0 + fy * (c1 - c0);
        const float R = r0 + fy * (r1 - r0);
        f4 resA, resB;
#pragma unroll
        for (int rr = 0; rr < 4; ++rr) {
            float fx = (2 * rr + 9) * (1.0f / 16.0f);
            resA[rr] = L + fx * (C - L);
        }
#pragma unroll
        for (int rr = 0; rr < 4; ++rr) {
            float fx = (2 * rr + 1) * (1.0f / 16.0f);
            resB[rr] = C + fx * (R - C);
        }
        f4* dst = (f4*)&out[outbase + rl * 512];
        __builtin_nontemporal_store(resA, dst);
        __builtin_nontemporal_store(resB, dst + 1);
    }
}

extern "C" void kernel_launch(void* const* d_in, const int* in_sizes, int n_in,
                              void* d_out, int out_size, void* d_ws, size_t ws_size,
                              hipStream_t stream) {
    const int*   x      = (const int*)d_in[0];
    const float* qtable = (const float*)d_in[1];
    const float* w0     = (const float*)d_in[2];
    const float* b0     = (const float*)d_in[3];
    const float* s0     = (const float*)d_in[4];
    const float* t0     = (const float*)d_in[5];
    const float* w1     = (const float*)d_in[6];
    const float* s1     = (const float*)d_in[7];
    const float* t1     = (const float*)d_in[8];
    const float* w2     = (const float*)d_in[9];
    const float* b2     = (const float*)d_in[10];
    const float* s2     = (const float*)d_in[11];
    const float* t2     = (const float*)d_in[12];

    float*    zbuf = (float*)d_ws;                       // 393,216 B
    _Float16* tabg = (_Float16*)((char*)d_ws + 393216);  // + 26,136 B + 512 B w1h
    float*    out  = (float*)d_out;

    const bool pre = ws_size >= (size_t)(393216 + TAB_N * 2 + 512);
    if (pre) {
        build_tab<<<50, 256, 0, stream>>>(w0, b0, s0, t0, w1, tabg);
        dct_stage1<true><<<2048, 512, 0, stream>>>(x, qtable, w0, b0, s0, t0,
                                                   w1, s1, t1, w2, b2, s2, t2,
                                                   tabg, zbuf);
    } else {
        dct_stage1<false><<<2048, 512, 0, stream>>>(x, qtable, w0, b0, s0, t0,
                                                    w1, s1, t1, w2, b2, s2, t2,
                                                    nullptr, zbuf);
    }
    upsample16<<<1536, 256, 0, stream>>>(zbuf, out);
}